// Round 3
// baseline (6277.744 us; speedup 1.0000x reference)
//
#include <hip/hip_runtime.h>
#include <hip/hip_bf16.h>
#include <math.h>

#define Bn 8
#define Sn 1024
#define Dn 512
#define Hn 8
#define HDn 64

// ---------------- Kernel 1: h = emb[x] + positional embedding ----------------
__global__ void k_embed(const int* __restrict__ x, const float* __restrict__ emb,
                        float* __restrict__ h) {
    const int total = Bn * Sn * Dn;
    for (int i = blockIdx.x * blockDim.x + threadIdx.x; i < total; i += gridDim.x * blockDim.x) {
        int d = i & (Dn - 1);
        int bs = i >> 9;           // b*S + s
        int s = bs & (Sn - 1);
        int tok = x[bs];
        // div = exp(2j * (-ln(10000)/512)), 2j = d with LSB cleared
        float f = expf((float)(d & ~1) * (-9.210340371976184f / 512.0f));
        float ang = (float)s * f;
        float pe = (d & 1) ? cosf(ang) : sinf(ang);
        h[i] = emb[(size_t)tok * Dn + d] + pe;
    }
}

// ---------------- Kernel 2: width[b,s] = h . Wc + bc (one wave per row) ------
__global__ void k_width(const float* __restrict__ h, const float* __restrict__ Wc,
                        const float* __restrict__ bc, float* __restrict__ width) {
    int row = blockIdx.x * 4 + (threadIdx.x >> 6);
    int lane = threadIdx.x & 63;
    const float* hr = h + (size_t)row * Dn;
    float acc = 0.f;
    for (int i = lane; i < Dn; i += 64) acc += hr[i] * Wc[i];
    for (int off = 32; off > 0; off >>= 1) acc += __shfl_down(acc, off);
    if (lane == 0) width[row] = acc + bc[0];
}

// ---------------- Kernel 3: per-batch min/max over S -------------------------
__global__ void k_minmax(const float* __restrict__ width, float* __restrict__ lo,
                         float* __restrict__ hi) {
    int b = blockIdx.x;
    __shared__ float smin[256], smax[256];
    float mn = 1e30f, mx = -1e30f;
    for (int s = threadIdx.x; s < Sn; s += 256) {
        float v = width[b * Sn + s];
        mn = fminf(mn, v);
        mx = fmaxf(mx, v);
    }
    smin[threadIdx.x] = mn; smax[threadIdx.x] = mx;
    __syncthreads();
    for (int off = 128; off; off >>= 1) {
        if (threadIdx.x < off) {
            smin[threadIdx.x] = fminf(smin[threadIdx.x], smin[threadIdx.x + off]);
            smax[threadIdx.x] = fmaxf(smax[threadIdx.x], smax[threadIdx.x + off]);
        }
        __syncthreads();
    }
    if (threadIdx.x == 0) { lo[b] = smin[0]; hi[b] = smax[0]; }
}

// ---------------- Kernel 4: mask -> f32 d_out tail ---------------------------
// idx_rolled[s,t] = (t - s + 511) mod 1024  (holds for ALL rows after the roll)
// move[s,t] = (s<512) ? (idx>=t) : (idx<t)
__global__ void k_mask(const float* __restrict__ width, const float* __restrict__ lo,
                       const float* __restrict__ hi, float* __restrict__ mask_out) {
    int bs = blockIdx.x;           // b*S + s
    int b = bs >> 10;
    int s = bs & (Sn - 1);
    float wn = (width[bs] - lo[b]) / (hi[b] - lo[b]);
    for (int t = threadIdx.x; t < Sn; t += 256) {
        int it = (t - s + 511) & (Sn - 1);
        float origin = (it < 512) ? (1.0f - (float)it * (1.0f / 511.0f))
                                  : ((float)(it - 512) * (1.0f / 511.0f));
        float z = (origin - wn) * 100.0f;
        // om = 1 - sigmoid(z) = sigmoid(-z), overflow-free both directions
        float om;
        if (z >= 0.0f) { float e = expf(-z); om = e / (1.0f + e); }
        else           { float e = expf(z);  om = 1.0f / (1.0f + e); }
        bool cmpv = (it >= t);
        bool mv = (s < 512) ? cmpv : !cmpv;
        mask_out[(size_t)bs * Sn + t] = mv ? om : 0.0f;
    }
}

// ---------------- Kernel 5: q,k,v = per-head 64x64 linears -------------------
// q/k/v stored as [B,H,S,HD] f32
__global__ void k_qkv(const float* __restrict__ h, const float* __restrict__ Wq,
                      const float* __restrict__ Wk, const float* __restrict__ Wv,
                      float* __restrict__ q, float* __restrict__ k, float* __restrict__ v) {
    __shared__ float hrow[Dn];
    int bs = blockIdx.x;           // b*S + s
    int t = threadIdx.x;           // 512 threads
    hrow[t] = h[(size_t)bs * Dn + t];
    __syncthreads();
    int head = t >> 6, o = t & 63;
    const float* hh = hrow + head * HDn;
    float aq = 0.f, ak = 0.f, av = 0.f;
    for (int d = 0; d < HDn; ++d) {
        float hv = hh[d];
        aq += hv * Wq[o * HDn + d];
        ak += hv * Wk[o * HDn + d];
        av += hv * Wv[o * HDn + d];
    }
    int b = bs >> 10, s = bs & (Sn - 1);
    size_t oidx = (((size_t)(b * Hn + head)) * Sn + s) * HDn + o;
    q[oidx] = aq; k[oidx] = ak; v[oidx] = av;
}

// ---------------- Kernel 6: attention, one block per (b,h,q-row) -------------
__global__ void k_attn(const float* __restrict__ q, const float* __restrict__ k,
                       const float* __restrict__ v, const float* __restrict__ maskf,
                       float* __restrict__ ao) {
    const float SCALE = 0.04419417382415922f;  // 1/sqrt(512)
    int gid = blockIdx.x;           // (b*H + h)*S + qs
    int qs = gid & (Sn - 1);
    int bh = gid >> 10;
    int hh = bh & (Hn - 1);
    int b = bh >> 3;
    __shared__ float qv[HDn];
    __shared__ float e[Sn];
    __shared__ float red[256];
    int t = threadIdx.x;
    const float* qptr = q + ((size_t)bh * Sn + qs) * HDn;
    if (t < HDn) qv[t] = qptr[t];
    __syncthreads();
    const float* kbase = k + (size_t)bh * Sn * HDn;
    const float* mrow = maskf + ((size_t)hh * Sn + qs) * Sn;   // mask[h,q,:] (B==H quirk)
    float lmax = -1e30f;
    for (int kk = t; kk < Sn; kk += 256) {
        const float* kr = kbase + (size_t)kk * HDn;
        float dot = 0.f;
        for (int o = 0; o < HDn; ++o) dot += qv[o] * kr[o];
        float ev = dot * mrow[kk] * SCALE;
        e[kk] = ev;
        lmax = fmaxf(lmax, ev);
    }
    red[t] = lmax; __syncthreads();
    for (int off = 128; off; off >>= 1) {
        if (t < off) red[t] = fmaxf(red[t], red[t + off]);
        __syncthreads();
    }
    float m = red[0];
    __syncthreads();
    float lsum = 0.f;
    for (int kk = t; kk < Sn; kk += 256) {
        float p = expf(e[kk] - m);
        e[kk] = p;
        lsum += p;
    }
    red[t] = lsum; __syncthreads();
    for (int off = 128; off; off >>= 1) {
        if (t < off) red[t] += red[t + off];
        __syncthreads();
    }
    float inv = 1.0f / red[0];
    __syncthreads();
    // P @ V : 4 groups of 64 lanes, each group sums 256 k's, coalesced on v
    int o = t & 63, g = t >> 6;
    const float* vbase = v + (size_t)bh * Sn * HDn;
    float acc = 0.f;
    for (int kk = g * 256; kk < g * 256 + 256; ++kk)
        acc += e[kk] * vbase[(size_t)kk * HDn + o];
    red[t] = acc; __syncthreads();
    if (g == 0) {
        float r = red[o] + red[64 + o] + red[128 + o] + red[192 + o];
        // ao layout [B,S,H,HD] == [B,S,D]
        ao[(((size_t)b * Sn + qs) * Hn + hh) * HDn + o] = r * inv;
    }
}

// ---------------- Kernel 7: out = ao @ Wo^T + bo (f32) -----------------------
__global__ void k_proj(const float* __restrict__ ao, const float* __restrict__ Wo,
                       const float* __restrict__ bo, float* __restrict__ out) {
    __shared__ float row[Dn];
    int bs = blockIdx.x;
    int t = threadIdx.x;           // 512 threads
    row[t] = ao[(size_t)bs * Dn + t];
    __syncthreads();
    float acc = bo[t];
    const float* wr = Wo + (size_t)t * Dn;
    for (int j = 0; j < Dn; ++j) acc += row[j] * wr[j];
    out[(size_t)bs * Dn + t] = acc;
}

extern "C" void kernel_launch(void* const* d_in, const int* in_sizes, int n_in,
                              void* d_out, int out_size, void* d_ws, size_t ws_size,
                              hipStream_t stream) {
    const int*   x   = (const int*)d_in[0];
    const float* emb = (const float*)d_in[1];
    const float* Wq  = (const float*)d_in[2];
    const float* Wk  = (const float*)d_in[3];
    const float* Wv  = (const float*)d_in[4];
    const float* Wo  = (const float*)d_in[5];
    const float* bo  = (const float*)d_in[6];
    const float* Wc  = (const float*)d_in[7];
    const float* bc  = (const float*)d_in[8];

    float* ws    = (float*)d_ws;
    float* h     = ws;                       // 4,194,304 f32 (reused as ao later)
    float* width = h + (size_t)Bn * Sn * Dn; // 8,192
    float* lo    = width + Bn * Sn;          // 8
    float* hi    = lo + Bn;                  // 8
    float* qb    = hi + Bn;
    float* kb    = qb + (size_t)Bn * Sn * Dn;
    float* vb    = kb + (size_t)Bn * Sn * Dn;
    float* ao    = h;                        // alias: h is dead after k_qkv

    float* out      = (float*)d_out;                      // [B,S,D]
    float* mask_out = out + (size_t)Bn * Sn * Dn;         // [B,S,S]

    k_embed<<<4096, 256, 0, stream>>>(x, emb, h);
    k_width<<<(Bn * Sn) / 4, 256, 0, stream>>>(h, Wc, bc, width);
    k_minmax<<<Bn, 256, 0, stream>>>(width, lo, hi);
    k_mask<<<Bn * Sn, 256, 0, stream>>>(width, lo, hi, mask_out);
    k_qkv<<<Bn * Sn, 512, 0, stream>>>(h, Wq, Wk, Wv, qb, kb, vb);
    k_attn<<<Bn * Hn * Sn, 256, 0, stream>>>(qb, kb, vb, mask_out, ao);
    k_proj<<<Bn * Sn, 512, 0, stream>>>(ao, Wo, bo, out);
}

// Round 4
// 654.034 us; speedup vs baseline: 9.5985x; 9.5985x over previous
//
#include <hip/hip_runtime.h>
#include <hip/hip_bf16.h>
#include <math.h>

#define Bn 8
#define Sn 1024
#define Dn 512
#define Hn 8
#define HDn 64

// ---------------- Kernel 1: h = emb[x] + positional embedding ----------------
__global__ void k_embed(const int* __restrict__ x, const float* __restrict__ emb,
                        float* __restrict__ h) {
    const int total = Bn * Sn * Dn;
    for (int i = blockIdx.x * blockDim.x + threadIdx.x; i < total; i += gridDim.x * blockDim.x) {
        int d = i & (Dn - 1);
        int bs = i >> 9;           // b*S + s
        int s = bs & (Sn - 1);
        int tok = x[bs];
        float f = __expf((float)(d & ~1) * (-9.210340371976184f / 512.0f));
        float ang = (float)s * f;
        float pe = (d & 1) ? __cosf(ang) : __sinf(ang);
        h[i] = emb[(size_t)tok * Dn + d] + pe;
    }
}

// ---------------- Kernel 2: width[b,s] = h . Wc + bc (one wave per row) ------
__global__ void k_width(const float* __restrict__ h, const float* __restrict__ Wc,
                        const float* __restrict__ bc, float* __restrict__ width) {
    int row = blockIdx.x * 4 + (threadIdx.x >> 6);
    int lane = threadIdx.x & 63;
    const float* hr = h + (size_t)row * Dn;
    float acc = 0.f;
    for (int i = lane; i < Dn; i += 64) acc += hr[i] * Wc[i];
    for (int off = 32; off > 0; off >>= 1) acc += __shfl_down(acc, off);
    if (lane == 0) width[row] = acc + bc[0];
}

// ---------------- Kernel 3: per-batch min/max over S -------------------------
__global__ void k_minmax(const float* __restrict__ width, float* __restrict__ lo,
                         float* __restrict__ hi) {
    int b = blockIdx.x;
    __shared__ float smin[256], smax[256];
    float mn = 1e30f, mx = -1e30f;
    for (int s = threadIdx.x; s < Sn; s += 256) {
        float v = width[b * Sn + s];
        mn = fminf(mn, v);
        mx = fmaxf(mx, v);
    }
    smin[threadIdx.x] = mn; smax[threadIdx.x] = mx;
    __syncthreads();
    for (int off = 128; off; off >>= 1) {
        if (threadIdx.x < off) {
            smin[threadIdx.x] = fminf(smin[threadIdx.x], smin[threadIdx.x + off]);
            smax[threadIdx.x] = fmaxf(smax[threadIdx.x], smax[threadIdx.x + off]);
        }
        __syncthreads();
    }
    if (threadIdx.x == 0) { lo[b] = smin[0]; hi[b] = smax[0]; }
}

// ---------------- Kernel 4: mask -> f32 d_out tail ---------------------------
__global__ void k_mask(const float* __restrict__ width, const float* __restrict__ lo,
                       const float* __restrict__ hi, float* __restrict__ mask_out) {
    int bs = blockIdx.x;           // b*S + s
    int b = bs >> 10;
    int s = bs & (Sn - 1);
    float wn = (width[bs] - lo[b]) / (hi[b] - lo[b]);
    for (int t = threadIdx.x; t < Sn; t += 256) {
        int it = (t - s + 511) & (Sn - 1);
        float origin = (it < 512) ? (1.0f - (float)it * (1.0f / 511.0f))
                                  : ((float)(it - 512) * (1.0f / 511.0f));
        float z = (origin - wn) * 100.0f;
        float om;
        if (z >= 0.0f) { float e = __expf(-z); om = e / (1.0f + e); }
        else           { float e = __expf(z);  om = 1.0f / (1.0f + e); }
        bool cmpv = (it >= t);
        bool mv = (s < 512) ? cmpv : !cmpv;
        mask_out[(size_t)bs * Sn + t] = mv ? om : 0.0f;
    }
}

// ---------------- Kernel 5: q,k,v — weights transposed in LDS, 8 tok/block ---
__global__ void k_qkv(const float* __restrict__ h, const float* __restrict__ Wq,
                      const float* __restrict__ Wk, const float* __restrict__ Wv,
                      float* __restrict__ q, float* __restrict__ k, float* __restrict__ v) {
    __shared__ float Hs[8][Dn];          // 16 KB
    __shared__ float WqS[HDn][HDn + 1];  // [d][o], padded
    __shared__ float WkS[HDn][HDn + 1];
    __shared__ float WvS[HDn][HDn + 1];
    int t = threadIdx.x;                 // 512 threads
    int bs0 = blockIdx.x * 8;
    for (int i = t; i < HDn * HDn; i += 512) {
        int o = i >> 6, d = i & 63;
        WqS[d][o] = Wq[i]; WkS[d][o] = Wk[i]; WvS[d][o] = Wv[i];
    }
    for (int i = t; i < 8 * Dn; i += 512) Hs[i >> 9][i & 511] = h[(size_t)bs0 * Dn + i];
    __syncthreads();
    int head = t >> 6, o = t & 63;       // one wave per head
    float aq[8] = {}, ak[8] = {}, av[8] = {};
    for (int d = 0; d < HDn; ++d) {
        float wq = WqS[d][o], wk = WkS[d][o], wv = WvS[d][o];
        #pragma unroll
        for (int tt = 0; tt < 8; ++tt) {
            float hv = Hs[tt][head * HDn + d];   // wave-uniform broadcast
            aq[tt] += hv * wq; ak[tt] += hv * wk; av[tt] += hv * wv;
        }
    }
    #pragma unroll
    for (int tt = 0; tt < 8; ++tt) {
        int bs = bs0 + tt;
        int b = bs >> 10, s = bs & (Sn - 1);
        size_t oidx = (((size_t)(b * Hn + head)) * Sn + s) * HDn + o;
        q[oidx] = aq[tt]; k[oidx] = ak[tt]; v[oidx] = av[tt];
    }
}

// ---------------- Kernel 6: flash attention, 64-q tile per block -------------
// grid: (b*H + h)*16 + qtile ; 256 threads = 16x16, micro 4x4
__global__ void k_attn(const float* __restrict__ q, const float* __restrict__ k,
                       const float* __restrict__ v, const float* __restrict__ maskf,
                       float* __restrict__ ao) {
    const float SCALE = 0.04419417382415922f;  // 1/sqrt(512)
    __shared__ float Qs[64][65];
    __shared__ float Ks[64][65];
    __shared__ float Vs[64][65];
    __shared__ float Ss[64][65];
    __shared__ float mrow[64], lrow[64], arow[64];
    int blk = blockIdx.x;
    int qt = blk & 15;
    int bh = blk >> 4;
    int hh = bh & (Hn - 1);
    int b = bh >> 3;
    int q0 = qt * 64;
    int t = threadIdx.x;
    int tx = t & 15, ty = t >> 4;
    const float* qbase = q + ((size_t)bh * Sn + q0) * HDn;
    for (int i = t; i < 64 * HDn; i += 256) Qs[i >> 6][i & 63] = qbase[i];
    if (t < 64) { mrow[t] = -1e30f; lrow[t] = 0.f; }
    float O[4][4] = {};
    __syncthreads();
    const float* kbase = k + (size_t)bh * Sn * HDn;
    const float* vbase = v + (size_t)bh * Sn * HDn;
    const float* mbase = maskf + ((size_t)hh * Sn + q0) * Sn;  // mask[h,q0+qr,:] (B==H quirk)
    for (int k0 = 0; k0 < Sn; k0 += 64) {
        for (int i = t; i < 64 * HDn; i += 256) {
            Ks[i >> 6][i & 63] = kbase[(size_t)k0 * HDn + i];
            Vs[i >> 6][i & 63] = vbase[(size_t)k0 * HDn + i];
        }
        __syncthreads();
        // S = (Q K^T) * mask * scale
        float acc[4][4] = {};
        for (int d = 0; d < HDn; ++d) {
            float qv[4], kv[4];
            #pragma unroll
            for (int i = 0; i < 4; ++i) qv[i] = Qs[4 * ty + i][d];
            #pragma unroll
            for (int j = 0; j < 4; ++j) kv[j] = Ks[4 * tx + j][d];
            #pragma unroll
            for (int i = 0; i < 4; ++i)
                #pragma unroll
                for (int j = 0; j < 4; ++j) acc[i][j] += qv[i] * kv[j];
        }
        #pragma unroll
        for (int i = 0; i < 4; ++i) {
            const float* mr = mbase + (size_t)(4 * ty + i) * Sn + k0;
            #pragma unroll
            for (int j = 0; j < 4; ++j)
                Ss[4 * ty + i][4 * tx + j] = acc[i][j] * mr[4 * tx + j] * SCALE;
        }
        __syncthreads();
        // online softmax, 4 lanes per row
        {
            int r = t >> 2, seg = t & 3;
            float lm = -1e30f;
            for (int c = seg * 16; c < seg * 16 + 16; ++c) lm = fmaxf(lm, Ss[r][c]);
            lm = fmaxf(lm, __shfl_xor(lm, 1));
            lm = fmaxf(lm, __shfl_xor(lm, 2));
            float mold = mrow[r];
            float mnew = fmaxf(mold, lm);
            float ps = 0.f;
            for (int c = seg * 16; c < seg * 16 + 16; ++c) {
                float p = __expf(Ss[r][c] - mnew);
                Ss[r][c] = p;
                ps += p;
            }
            ps += __shfl_xor(ps, 1);
            ps += __shfl_xor(ps, 2);
            if (seg == 0) {
                float al = __expf(mold - mnew);
                arow[r] = al;
                lrow[r] = lrow[r] * al + ps;
                mrow[r] = mnew;
            }
        }
        __syncthreads();
        // O = O*alpha + P V
        float al[4];
        #pragma unroll
        for (int i = 0; i < 4; ++i) al[i] = arow[4 * ty + i];
        #pragma unroll
        for (int i = 0; i < 4; ++i)
            #pragma unroll
            for (int j = 0; j < 4; ++j) O[i][j] *= al[i];
        for (int kk = 0; kk < 64; ++kk) {
            float pv[4], vv[4];
            #pragma unroll
            for (int i = 0; i < 4; ++i) pv[i] = Ss[4 * ty + i][kk];
            #pragma unroll
            for (int j = 0; j < 4; ++j) vv[j] = Vs[kk][4 * tx + j];
            #pragma unroll
            for (int i = 0; i < 4; ++i)
                #pragma unroll
                for (int j = 0; j < 4; ++j) O[i][j] += pv[i] * vv[j];
        }
        __syncthreads();
    }
    float linv[4];
    #pragma unroll
    for (int i = 0; i < 4; ++i) linv[i] = 1.0f / lrow[4 * ty + i];
    #pragma unroll
    for (int i = 0; i < 4; ++i)
        #pragma unroll
        for (int j = 0; j < 4; ++j)
            ao[((size_t)b * Sn + q0 + 4 * ty + i) * Dn + hh * HDn + 4 * tx + j] = O[i][j] * linv[i];
}

// ---------------- Kernel 7: out = ao @ Wo^T + bo, tiled GEMM -----------------
// grid: 128 m-tiles x 8 n-tiles; 256 threads = 16x16, micro 4x4
__global__ void k_proj(const float* __restrict__ ao, const float* __restrict__ Wo,
                       const float* __restrict__ bo, float* __restrict__ out) {
    __shared__ float As[64][65];
    __shared__ float Bs[64][65];   // Bs[k][n] = Wo[n0+n][k0+k]
    int bm = blockIdx.x >> 3;
    int bn = blockIdx.x & 7;
    int t = threadIdx.x;
    int tx = t & 15, ty = t >> 4;
    int m0 = bm * 64, n0 = bn * 64;
    float acc[4][4] = {};
    for (int k0 = 0; k0 < Dn; k0 += 64) {
        for (int i = t; i < 4096; i += 256)
            As[i >> 6][i & 63] = ao[(size_t)(m0 + (i >> 6)) * Dn + k0 + (i & 63)];
        for (int i = t; i < 4096; i += 256) {
            int n = i >> 6, kk = i & 63;
            Bs[kk][n] = Wo[(size_t)(n0 + n) * Dn + k0 + kk];
        }
        __syncthreads();
        for (int kk = 0; kk < 64; ++kk) {
            float a4[4], b4[4];
            #pragma unroll
            for (int i = 0; i < 4; ++i) a4[i] = As[4 * ty + i][kk];
            #pragma unroll
            for (int j = 0; j < 4; ++j) b4[j] = Bs[kk][4 * tx + j];
            #pragma unroll
            for (int i = 0; i < 4; ++i)
                #pragma unroll
                for (int j = 0; j < 4; ++j) acc[i][j] += a4[i] * b4[j];
        }
        __syncthreads();
    }
    #pragma unroll
    for (int i = 0; i < 4; ++i)
        #pragma unroll
        for (int j = 0; j < 4; ++j)
            out[(size_t)(m0 + 4 * ty + i) * Dn + n0 + 4 * tx + j] = acc[i][j] + bo[n0 + 4 * tx + j];
}

extern "C" void kernel_launch(void* const* d_in, const int* in_sizes, int n_in,
                              void* d_out, int out_size, void* d_ws, size_t ws_size,
                              hipStream_t stream) {
    const int*   x   = (const int*)d_in[0];
    const float* emb = (const float*)d_in[1];
    const float* Wq  = (const float*)d_in[2];
    const float* Wk  = (const float*)d_in[3];
    const float* Wv  = (const float*)d_in[4];
    const float* Wo  = (const float*)d_in[5];
    const float* bo  = (const float*)d_in[6];
    const float* Wc  = (const float*)d_in[7];
    const float* bc  = (const float*)d_in[8];

    float* ws    = (float*)d_ws;
    float* h     = ws;                       // reused as ao after k_qkv
    float* width = h + (size_t)Bn * Sn * Dn;
    float* lo    = width + Bn * Sn;
    float* hi    = lo + Bn;
    float* qb    = hi + Bn;
    float* kb    = qb + (size_t)Bn * Sn * Dn;
    float* vb    = kb + (size_t)Bn * Sn * Dn;
    float* ao    = h;                        // h dead after k_qkv

    float* out      = (float*)d_out;                      // [B,S,D]
    float* mask_out = out + (size_t)Bn * Sn * Dn;         // [B,S,S]

    k_embed<<<4096, 256, 0, stream>>>(x, emb, h);
    k_width<<<(Bn * Sn) / 4, 256, 0, stream>>>(h, Wc, bc, width);
    k_minmax<<<Bn, 256, 0, stream>>>(width, lo, hi);
    k_mask<<<Bn * Sn, 256, 0, stream>>>(width, lo, hi, mask_out);
    k_qkv<<<(Bn * Sn) / 8, 512, 0, stream>>>(h, Wq, Wk, Wv, qb, kb, vb);
    k_attn<<<Bn * Hn * (Sn / 64), 256, 0, stream>>>(qb, kb, vb, mask_out, ao);
    k_proj<<<(Bn * Sn / 64) * (Dn / 64), 256, 0, stream>>>(ao, Wo, bo, out);
}

// Round 5
// 343.879 us; speedup vs baseline: 18.2557x; 1.9019x over previous
//
#include <hip/hip_runtime.h>
#include <hip/hip_bf16.h>
#include <math.h>

#define Bn 8
#define Sn 1024
#define Dn 512
#define Hn 8
#define HDn 64

typedef __bf16 bf16x8 __attribute__((ext_vector_type(8)));
typedef float  f32x4  __attribute__((ext_vector_type(4)));

// ---------------- Kernel 1: h = emb[x] + positional embedding ----------------
__global__ void k_embed(const int* __restrict__ x, const float* __restrict__ emb,
                        float* __restrict__ h) {
    const int total = Bn * Sn * Dn;
    for (int i = blockIdx.x * blockDim.x + threadIdx.x; i < total; i += gridDim.x * blockDim.x) {
        int d = i & (Dn - 1);
        int bs = i >> 9;           // b*S + s
        int s = bs & (Sn - 1);
        int tok = x[bs];
        float f = __expf((float)(d & ~1) * (-9.210340371976184f / 512.0f));
        float ang = (float)s * f;
        float pe = (d & 1) ? __cosf(ang) : __sinf(ang);
        h[i] = emb[(size_t)tok * Dn + d] + pe;
    }
}

// ---------------- Kernel 2: width[b,s] = h . Wc + bc (one wave per row) ------
__global__ void k_width(const float* __restrict__ h, const float* __restrict__ Wc,
                        const float* __restrict__ bc, float* __restrict__ width) {
    int row = blockIdx.x * 4 + (threadIdx.x >> 6);
    int lane = threadIdx.x & 63;
    const float* hr = h + (size_t)row * Dn;
    float acc = 0.f;
    for (int i = lane; i < Dn; i += 64) acc += hr[i] * Wc[i];
    for (int off = 32; off > 0; off >>= 1) acc += __shfl_down(acc, off);
    if (lane == 0) width[row] = acc + bc[0];
}

// ---------------- Kernel 3: per-batch min/max over S -------------------------
__global__ void k_minmax(const float* __restrict__ width, float* __restrict__ lo,
                         float* __restrict__ hi) {
    int b = blockIdx.x;
    __shared__ float smin[256], smax[256];
    float mn = 1e30f, mx = -1e30f;
    for (int s = threadIdx.x; s < Sn; s += 256) {
        float v = width[b * Sn + s];
        mn = fminf(mn, v);
        mx = fmaxf(mx, v);
    }
    smin[threadIdx.x] = mn; smax[threadIdx.x] = mx;
    __syncthreads();
    for (int off = 128; off; off >>= 1) {
        if (threadIdx.x < off) {
            smin[threadIdx.x] = fminf(smin[threadIdx.x], smin[threadIdx.x + off]);
            smax[threadIdx.x] = fmaxf(smax[threadIdx.x], smax[threadIdx.x + off]);
        }
        __syncthreads();
    }
    if (threadIdx.x == 0) { lo[b] = smin[0]; hi[b] = smax[0]; }
}

// ---------------- Kernel 4: mask -> f32 d_out tail ---------------------------
__global__ void k_mask(const float* __restrict__ width, const float* __restrict__ lo,
                       const float* __restrict__ hi, float* __restrict__ mask_out) {
    int bs = blockIdx.x;           // b*S + s
    int b = bs >> 10;
    int s = bs & (Sn - 1);
    float wn = (width[bs] - lo[b]) / (hi[b] - lo[b]);
    for (int t = threadIdx.x; t < Sn; t += 256) {
        int it = (t - s + 511) & (Sn - 1);
        float origin = (it < 512) ? (1.0f - (float)it * (1.0f / 511.0f))
                                  : ((float)(it - 512) * (1.0f / 511.0f));
        float z = (origin - wn) * 100.0f;
        float om;
        if (z >= 0.0f) { float e = __expf(-z); om = e / (1.0f + e); }
        else           { float e = __expf(z);  om = 1.0f / (1.0f + e); }
        bool cmpv = (it >= t);
        bool mv = (s < 512) ? cmpv : !cmpv;
        mask_out[(size_t)bs * Sn + t] = mv ? om : 0.0f;
    }
}

// ---------------- Kernel 5: q,k,v — f32 math, bf16 outputs -------------------
// q,k: [B,H,S,HD] bf16 ; vt: [B,H,HD,S] bf16 (pre-transposed for PV MFMA)
__global__ void k_qkv(const float* __restrict__ h, const float* __restrict__ Wq,
                      const float* __restrict__ Wk, const float* __restrict__ Wv,
                      __bf16* __restrict__ q, __bf16* __restrict__ k, __bf16* __restrict__ vt) {
    __shared__ float Hs[8][Dn];          // 16 KB
    __shared__ float WqS[HDn][HDn + 1];  // [d][o], padded
    __shared__ float WkS[HDn][HDn + 1];
    __shared__ float WvS[HDn][HDn + 1];
    int t = threadIdx.x;                 // 512 threads
    int bs0 = blockIdx.x * 8;
    for (int i = t; i < HDn * HDn; i += 512) {
        int o = i >> 6, d = i & 63;
        WqS[d][o] = Wq[i]; WkS[d][o] = Wk[i]; WvS[d][o] = Wv[i];
    }
    for (int i = t; i < 8 * Dn; i += 512) Hs[i >> 9][i & 511] = h[(size_t)bs0 * Dn + i];
    __syncthreads();
    int head = t >> 6, o = t & 63;       // one wave per head
    float aq[8] = {}, ak[8] = {}, av[8] = {};
    for (int d = 0; d < HDn; ++d) {
        float wq = WqS[d][o], wk = WkS[d][o], wv = WvS[d][o];
        #pragma unroll
        for (int tt = 0; tt < 8; ++tt) {
            float hv = Hs[tt][head * HDn + d];   // wave-uniform broadcast
            aq[tt] += hv * wq; ak[tt] += hv * wk; av[tt] += hv * wv;
        }
    }
    int b = bs0 >> 10, s0 = bs0 & (Sn - 1);
    int bh = b * Hn + head;
    __bf16 vloc[8];
    #pragma unroll
    for (int tt = 0; tt < 8; ++tt) {
        size_t oidx = ((size_t)bh * Sn + s0 + tt) * HDn + o;
        q[oidx] = (__bf16)aq[tt];
        k[oidx] = (__bf16)ak[tt];
        vloc[tt] = (__bf16)av[tt];
    }
    *(bf16x8*)&vt[((size_t)bh * HDn + o) * Sn + s0] = *(bf16x8*)vloc;
}

// ---------------- Kernel 6: MFMA flash attention -----------------------------
// grid: (b*H+h)*16 + qtile ; 256 thr = 4 waves; wave w owns q-rows [w*16,w*16+16)
// mfma_f32_16x16x32_bf16 layouts (HW-verified): A[m=lane&15][k=quad*8+j],
// B[k=quad*8+j][n=lane&15], C/D row=quad*4+reg col=lane&15.
__global__ __launch_bounds__(256) void k_attn(
        const __bf16* __restrict__ q, const __bf16* __restrict__ k,
        const __bf16* __restrict__ vt, const float* __restrict__ maskf,
        float* __restrict__ ao) {
    const float SCALE = 0.04419417382415922f;  // 1/sqrt(512)
    __shared__ __align__(16) __bf16 Qs[64][72];   // pad 72: 2-way max (free)
    __shared__ __align__(16) __bf16 Ks[64][72];
    __shared__ __align__(16) __bf16 Vt[64][72];   // [o][k_local]
    __shared__ __align__(16) __bf16 Ps[64][72];
    int blk = blockIdx.x;
    int qt = blk & 15;
    int bh = blk >> 4;
    int hh = bh & (Hn - 1);
    int b = bh >> 3;
    int q0 = qt * 64;
    int t = threadIdx.x;
    int w = t >> 6, lane = t & 63, quad = lane >> 4, li = lane & 15;

    const __bf16* qbase  = q  + ((size_t)bh * Sn + q0) * HDn;
    const __bf16* kbase  = k  + (size_t)bh * Sn * HDn;
    const __bf16* vtbase = vt + (size_t)bh * HDn * Sn;
    const float*  mbase  = maskf + ((size_t)hh * Sn + q0) * Sn;  // B==H quirk

    #pragma unroll
    for (int it = 0; it < 2; ++it) {
        int e = (it * 256 + t) * 8; int r = e >> 6, c = e & 63;
        *(bf16x8*)&Qs[r][c] = *(const bf16x8*)&qbase[e];
    }

    f32x4 O[4];
    #pragma unroll
    for (int n = 0; n < 4; ++n) O[n] = (f32x4){0.f, 0.f, 0.f, 0.f};
    float m_[4] = {-1e30f, -1e30f, -1e30f, -1e30f};
    float l_[4] = {0.f, 0.f, 0.f, 0.f};

    for (int k0 = 0; k0 < Sn; k0 += 64) {
        if (k0) __syncthreads();       // prior tile's reads done before restage
        #pragma unroll
        for (int it = 0; it < 2; ++it) {
            int e = (it * 256 + t) * 8; int r = e >> 6, c = e & 63;
            *(bf16x8*)&Ks[r][c] = *(const bf16x8*)&kbase[(size_t)k0 * HDn + e];
            *(bf16x8*)&Vt[r][c] = *(const bf16x8*)&vtbase[(size_t)r * Sn + k0 + c];
        }
        __syncthreads();

        // ---- S = Q K^T (f32 acc) ----
        bf16x8 A0 = *(const bf16x8*)&Qs[w * 16 + li][quad * 8];
        bf16x8 A1 = *(const bf16x8*)&Qs[w * 16 + li][32 + quad * 8];
        f32x4 Sf[4];
        #pragma unroll
        for (int n = 0; n < 4; ++n) {
            f32x4 acc = (f32x4){0.f, 0.f, 0.f, 0.f};
            bf16x8 B0 = *(const bf16x8*)&Ks[n * 16 + li][quad * 8];
            acc = __builtin_amdgcn_mfma_f32_16x16x32_bf16(A0, B0, acc, 0, 0, 0);
            bf16x8 B1 = *(const bf16x8*)&Ks[n * 16 + li][32 + quad * 8];
            acc = __builtin_amdgcn_mfma_f32_16x16x32_bf16(A1, B1, acc, 0, 0, 0);
            Sf[n] = acc;
        }
        // ---- mask * scale ----
        #pragma unroll
        for (int n = 0; n < 4; ++n)
            #pragma unroll
            for (int r = 0; r < 4; ++r)
                Sf[n][r] *= mbase[(size_t)(w * 16 + quad * 4 + r) * Sn + k0 + n * 16 + li] * SCALE;

        // ---- online softmax (rows live in quads; reduce over 16 lanes) ----
        float mx[4];
        #pragma unroll
        for (int r = 0; r < 4; ++r)
            mx[r] = fmaxf(fmaxf(Sf[0][r], Sf[1][r]), fmaxf(Sf[2][r], Sf[3][r]));
        #pragma unroll
        for (int off = 1; off < 16; off <<= 1)
            #pragma unroll
            for (int r = 0; r < 4; ++r) mx[r] = fmaxf(mx[r], __shfl_xor(mx[r], off));
        float al[4], rs[4] = {0.f, 0.f, 0.f, 0.f};
        #pragma unroll
        for (int r = 0; r < 4; ++r) {
            float mn = fmaxf(m_[r], mx[r]);
            al[r] = __expf(m_[r] - mn);
            m_[r] = mn;
        }
        float p[4][4];
        #pragma unroll
        for (int n = 0; n < 4; ++n)
            #pragma unroll
            for (int r = 0; r < 4; ++r) {
                p[n][r] = __expf(Sf[n][r] - m_[r]);
                rs[r] += p[n][r];
            }
        #pragma unroll
        for (int off = 1; off < 16; off <<= 1)
            #pragma unroll
            for (int r = 0; r < 4; ++r) rs[r] += __shfl_xor(rs[r], off);
        #pragma unroll
        for (int r = 0; r < 4; ++r) l_[r] = l_[r] * al[r] + rs[r];
        #pragma unroll
        for (int n = 0; n < 4; ++n)
            #pragma unroll
            for (int r = 0; r < 4; ++r) O[n][r] *= al[r];

        // ---- P -> LDS (C-layout rows -> A-layout rows; within-wave only) ----
        #pragma unroll
        for (int n = 0; n < 4; ++n)
            #pragma unroll
            for (int r = 0; r < 4; ++r)
                Ps[w * 16 + quad * 4 + r][n * 16 + li] = (__bf16)p[n][r];

        // ---- O += P V ----
        #pragma unroll
        for (int kc = 0; kc < 2; ++kc) {
            bf16x8 Ap = *(const bf16x8*)&Ps[w * 16 + li][kc * 32 + quad * 8];
            #pragma unroll
            for (int n = 0; n < 4; ++n) {
                bf16x8 Bv = *(const bf16x8*)&Vt[n * 16 + li][kc * 32 + quad * 8];
                O[n] = __builtin_amdgcn_mfma_f32_16x16x32_bf16(Ap, Bv, O[n], 0, 0, 0);
            }
        }
    }

    float inv[4];
    #pragma unroll
    for (int r = 0; r < 4; ++r) inv[r] = 1.0f / l_[r];
    #pragma unroll
    for (int n = 0; n < 4; ++n)
        #pragma unroll
        for (int r = 0; r < 4; ++r)
            ao[((size_t)b * Sn + q0 + w * 16 + quad * 4 + r) * Dn + hh * HDn + n * 16 + li]
                = O[n][r] * inv[r];
}

// ---------------- Kernel 7: out = ao @ Wo^T + bo, tiled GEMM -----------------
__global__ void k_proj(const float* __restrict__ ao, const float* __restrict__ Wo,
                       const float* __restrict__ bo, float* __restrict__ out) {
    __shared__ float As[64][65];
    __shared__ float Bs[64][65];   // Bs[k][n] = Wo[n0+n][k0+k]
    int bm = blockIdx.x >> 3;
    int bn = blockIdx.x & 7;
    int t = threadIdx.x;
    int tx = t & 15, ty = t >> 4;
    int m0 = bm * 64, n0 = bn * 64;
    float acc[4][4] = {};
    for (int k0 = 0; k0 < Dn; k0 += 64) {
        for (int i = t; i < 4096; i += 256)
            As[i >> 6][i & 63] = ao[(size_t)(m0 + (i >> 6)) * Dn + k0 + (i & 63)];
        for (int i = t; i < 4096; i += 256) {
            int n = i >> 6, kk = i & 63;
            Bs[kk][n] = Wo[(size_t)(n0 + n) * Dn + k0 + kk];
        }
        __syncthreads();
        for (int kk = 0; kk < 64; ++kk) {
            float a4[4], b4[4];
            #pragma unroll
            for (int i = 0; i < 4; ++i) a4[i] = As[4 * ty + i][kk];
            #pragma unroll
            for (int j = 0; j < 4; ++j) b4[j] = Bs[kk][4 * tx + j];
            #pragma unroll
            for (int i = 0; i < 4; ++i)
                #pragma unroll
                for (int j = 0; j < 4; ++j) acc[i][j] += a4[i] * b4[j];
        }
        __syncthreads();
    }
    #pragma unroll
    for (int i = 0; i < 4; ++i)
        #pragma unroll
        for (int j = 0; j < 4; ++j)
            out[(size_t)(m0 + 4 * ty + i) * Dn + n0 + 4 * tx + j] = acc[i][j] + bo[n0 + 4 * tx + j];
}

extern "C" void kernel_launch(void* const* d_in, const int* in_sizes, int n_in,
                              void* d_out, int out_size, void* d_ws, size_t ws_size,
                              hipStream_t stream) {
    const int*   x   = (const int*)d_in[0];
    const float* emb = (const float*)d_in[1];
    const float* Wq  = (const float*)d_in[2];
    const float* Wk  = (const float*)d_in[3];
    const float* Wv  = (const float*)d_in[4];
    const float* Wo  = (const float*)d_in[5];
    const float* bo  = (const float*)d_in[6];
    const float* Wc  = (const float*)d_in[7];
    const float* bc  = (const float*)d_in[8];

    float* ws    = (float*)d_ws;
    float* h     = ws;                       // reused as ao after k_qkv
    float* width = h + (size_t)Bn * Sn * Dn;
    float* lo    = width + Bn * Sn;
    float* hi    = lo + Bn;
    __bf16* qb   = (__bf16*)(hi + Bn);       // [B,H,S,HD]
    __bf16* kb   = qb + (size_t)Bn * Sn * Dn;
    __bf16* vtb  = kb + (size_t)Bn * Sn * Dn; // [B,H,HD,S]
    float* ao    = h;                        // h dead after k_qkv

    float* out      = (float*)d_out;                      // [B,S,D]
    float* mask_out = out + (size_t)Bn * Sn * Dn;         // [B,S,S]

    k_embed<<<4096, 256, 0, stream>>>(x, emb, h);
    k_width<<<(Bn * Sn) / 4, 256, 0, stream>>>(h, Wc, bc, width);
    k_minmax<<<Bn, 256, 0, stream>>>(width, lo, hi);
    k_mask<<<Bn * Sn, 256, 0, stream>>>(width, lo, hi, mask_out);
    k_qkv<<<(Bn * Sn) / 8, 512, 0, stream>>>(h, Wq, Wk, Wv, qb, kb, vtb);
    k_attn<<<Bn * Hn * (Sn / 64), 256, 0, stream>>>(qb, kb, vtb, mask_out, ao);
    k_proj<<<(Bn * Sn / 64) * (Dn / 64), 256, 0, stream>>>(ao, Wo, bo, out);
}

// Round 6
// 255.182 us; speedup vs baseline: 24.6010x; 1.3476x over previous
//
#include <hip/hip_runtime.h>
#include <hip/hip_bf16.h>
#include <math.h>

#define Bn 8
#define Sn 1024
#define Dn 512
#define Hn 8
#define HDn 64

typedef __bf16 bf16x8 __attribute__((ext_vector_type(8)));
typedef __bf16 bf16x4 __attribute__((ext_vector_type(4)));
typedef float  f32x4  __attribute__((ext_vector_type(4)));

// ---------------- Kernel 1: h = emb[x] + positional embedding ----------------
__global__ void k_embed(const int* __restrict__ x, const float* __restrict__ emb,
                        float* __restrict__ h) {
    const int total = Bn * Sn * Dn;
    for (int i = blockIdx.x * blockDim.x + threadIdx.x; i < total; i += gridDim.x * blockDim.x) {
        int d = i & (Dn - 1);
        int bs = i >> 9;           // b*S + s
        int s = bs & (Sn - 1);
        int tok = x[bs];
        float f = __expf((float)(d & ~1) * (-9.210340371976184f / 512.0f));
        float ang = (float)s * f;
        float pe = (d & 1) ? __cosf(ang) : __sinf(ang);
        h[i] = emb[(size_t)tok * Dn + d] + pe;
    }
}

// ---------------- Kernel 2: width[b,s] = h . Wc + bc (one wave per row) ------
__global__ void k_width(const float* __restrict__ h, const float* __restrict__ Wc,
                        const float* __restrict__ bc, float* __restrict__ width) {
    int row = blockIdx.x * 4 + (threadIdx.x >> 6);
    int lane = threadIdx.x & 63;
    const float* hr = h + (size_t)row * Dn;
    float acc = 0.f;
    for (int i = lane; i < Dn; i += 64) acc += hr[i] * Wc[i];
    for (int off = 32; off > 0; off >>= 1) acc += __shfl_down(acc, off);
    if (lane == 0) width[row] = acc + bc[0];
}

// ---------------- Kernel 3: per-batch min/max over S -------------------------
__global__ void k_minmax(const float* __restrict__ width, float* __restrict__ lo,
                         float* __restrict__ hi) {
    int b = blockIdx.x;
    __shared__ float smin[256], smax[256];
    float mn = 1e30f, mx = -1e30f;
    for (int s = threadIdx.x; s < Sn; s += 256) {
        float v = width[b * Sn + s];
        mn = fminf(mn, v);
        mx = fmaxf(mx, v);
    }
    smin[threadIdx.x] = mn; smax[threadIdx.x] = mx;
    __syncthreads();
    for (int off = 128; off; off >>= 1) {
        if (threadIdx.x < off) {
            smin[threadIdx.x] = fminf(smin[threadIdx.x], smin[threadIdx.x + off]);
            smax[threadIdx.x] = fmaxf(smax[threadIdx.x], smax[threadIdx.x + off]);
        }
        __syncthreads();
    }
    if (threadIdx.x == 0) { lo[b] = smin[0]; hi[b] = smax[0]; }
}

// ---------------- Kernel 4: mask -> f32 d_out tail ---------------------------
__global__ void k_mask(const float* __restrict__ width, const float* __restrict__ lo,
                       const float* __restrict__ hi, float* __restrict__ mask_out) {
    int bs = blockIdx.x;           // b*S + s
    int b = bs >> 10;
    int s = bs & (Sn - 1);
    float wn = (width[bs] - lo[b]) / (hi[b] - lo[b]);
    for (int t = threadIdx.x; t < Sn; t += 256) {
        int it = (t - s + 511) & (Sn - 1);
        float origin = (it < 512) ? (1.0f - (float)it * (1.0f / 511.0f))
                                  : ((float)(it - 512) * (1.0f / 511.0f));
        float z = (origin - wn) * 100.0f;
        float om;
        if (z >= 0.0f) { float e = __expf(-z); om = e / (1.0f + e); }
        else           { float e = __expf(z);  om = 1.0f / (1.0f + e); }
        bool cmpv = (it >= t);
        bool mv = (s < 512) ? cmpv : !cmpv;
        mask_out[(size_t)bs * Sn + t] = mv ? om : 0.0f;
    }
}

// ---------------- Kernel 5: q,k,v — f32 math, bf16 outputs -------------------
// q,k: [B,H,S,HD] bf16 ; vt: [B,H,HD,S] bf16 (pre-transposed for PV MFMA)
__global__ void k_qkv(const float* __restrict__ h, const float* __restrict__ Wq,
                      const float* __restrict__ Wk, const float* __restrict__ Wv,
                      __bf16* __restrict__ q, __bf16* __restrict__ k, __bf16* __restrict__ vt) {
    __shared__ float Hs[8][Dn];          // 16 KB
    __shared__ float WqS[HDn][HDn + 1];  // [d][o], padded
    __shared__ float WkS[HDn][HDn + 1];
    __shared__ float WvS[HDn][HDn + 1];
    int t = threadIdx.x;                 // 512 threads
    int bs0 = blockIdx.x * 8;
    for (int i = t; i < HDn * HDn; i += 512) {
        int o = i >> 6, d = i & 63;
        WqS[d][o] = Wq[i]; WkS[d][o] = Wk[i]; WvS[d][o] = Wv[i];
    }
    for (int i = t; i < 8 * Dn; i += 512) Hs[i >> 9][i & 511] = h[(size_t)bs0 * Dn + i];
    __syncthreads();
    int head = t >> 6, o = t & 63;       // one wave per head
    float aq[8] = {}, ak[8] = {}, av[8] = {};
    for (int d = 0; d < HDn; ++d) {
        float wq = WqS[d][o], wk = WkS[d][o], wv = WvS[d][o];
        #pragma unroll
        for (int tt = 0; tt < 8; ++tt) {
            float hv = Hs[tt][head * HDn + d];   // wave-uniform broadcast
            aq[tt] += hv * wq; ak[tt] += hv * wk; av[tt] += hv * wv;
        }
    }
    int b = bs0 >> 10, s0 = bs0 & (Sn - 1);
    int bh = b * Hn + head;
    __bf16 vloc[8];
    #pragma unroll
    for (int tt = 0; tt < 8; ++tt) {
        size_t oidx = ((size_t)bh * Sn + s0 + tt) * HDn + o;
        q[oidx] = (__bf16)aq[tt];
        k[oidx] = (__bf16)ak[tt];
        vloc[tt] = (__bf16)av[tt];
    }
    *(bf16x8*)&vt[((size_t)bh * HDn + o) * Sn + s0] = *(bf16x8*)vloc;
}

// ---------------- Kernel 6: MFMA flash attention -----------------------------
// grid: (b*H+h)*16 + qtile ; 256 thr = 4 waves; wave w owns q-rows [w*16,w*16+16)
// mfma_f32_16x16x32_bf16 layouts (HW-verified): A[m=lane&15][k=quad*8+j],
// B[k=quad*8+j][n=lane&15], C/D row=quad*4+reg col=lane&15.
// ao written as bf16 [B,S,D] for the MFMA projection kernel.
__global__ __launch_bounds__(256) void k_attn(
        const __bf16* __restrict__ q, const __bf16* __restrict__ k,
        const __bf16* __restrict__ vt, const float* __restrict__ maskf,
        __bf16* __restrict__ ao) {
    const float SCALE = 0.04419417382415922f;  // 1/sqrt(512)
    __shared__ __align__(16) __bf16 Qs[64][72];   // pad 72: 2-way max (free)
    __shared__ __align__(16) __bf16 Ks[64][72];
    __shared__ __align__(16) __bf16 Vt[64][72];   // [o][k_local]
    __shared__ __align__(16) __bf16 Ps[64][72];
    int blk = blockIdx.x;
    int qt = blk & 15;
    int bh = blk >> 4;
    int hh = bh & (Hn - 1);
    int b = bh >> 3;
    int q0 = qt * 64;
    int t = threadIdx.x;
    int w = t >> 6, lane = t & 63, quad = lane >> 4, li = lane & 15;

    const __bf16* qbase  = q  + ((size_t)bh * Sn + q0) * HDn;
    const __bf16* kbase  = k  + (size_t)bh * Sn * HDn;
    const __bf16* vtbase = vt + (size_t)bh * HDn * Sn;
    const float*  mbase  = maskf + ((size_t)hh * Sn + q0) * Sn;  // B==H quirk

    #pragma unroll
    for (int it = 0; it < 2; ++it) {
        int e = (it * 256 + t) * 8; int r = e >> 6, c = e & 63;
        *(bf16x8*)&Qs[r][c] = *(const bf16x8*)&qbase[e];
    }

    f32x4 O[4];
    #pragma unroll
    for (int n = 0; n < 4; ++n) O[n] = (f32x4){0.f, 0.f, 0.f, 0.f};
    float m_[4] = {-1e30f, -1e30f, -1e30f, -1e30f};
    float l_[4] = {0.f, 0.f, 0.f, 0.f};

    for (int k0 = 0; k0 < Sn; k0 += 64) {
        if (k0) __syncthreads();       // prior tile's reads done before restage
        #pragma unroll
        for (int it = 0; it < 2; ++it) {
            int e = (it * 256 + t) * 8; int r = e >> 6, c = e & 63;
            *(bf16x8*)&Ks[r][c] = *(const bf16x8*)&kbase[(size_t)k0 * HDn + e];
            *(bf16x8*)&Vt[r][c] = *(const bf16x8*)&vtbase[(size_t)r * Sn + k0 + c];
        }
        __syncthreads();

        // ---- S = Q K^T (f32 acc) ----
        bf16x8 A0 = *(const bf16x8*)&Qs[w * 16 + li][quad * 8];
        bf16x8 A1 = *(const bf16x8*)&Qs[w * 16 + li][32 + quad * 8];
        f32x4 Sf[4];
        #pragma unroll
        for (int n = 0; n < 4; ++n) {
            f32x4 acc = (f32x4){0.f, 0.f, 0.f, 0.f};
            bf16x8 B0 = *(const bf16x8*)&Ks[n * 16 + li][quad * 8];
            acc = __builtin_amdgcn_mfma_f32_16x16x32_bf16(A0, B0, acc, 0, 0, 0);
            bf16x8 B1 = *(const bf16x8*)&Ks[n * 16 + li][32 + quad * 8];
            acc = __builtin_amdgcn_mfma_f32_16x16x32_bf16(A1, B1, acc, 0, 0, 0);
            Sf[n] = acc;
        }
        // ---- mask * scale ----
        #pragma unroll
        for (int n = 0; n < 4; ++n)
            #pragma unroll
            for (int r = 0; r < 4; ++r)
                Sf[n][r] *= mbase[(size_t)(w * 16 + quad * 4 + r) * Sn + k0 + n * 16 + li] * SCALE;

        // ---- online softmax (rows live in quads; reduce over 16 lanes) ----
        float mx[4];
        #pragma unroll
        for (int r = 0; r < 4; ++r)
            mx[r] = fmaxf(fmaxf(Sf[0][r], Sf[1][r]), fmaxf(Sf[2][r], Sf[3][r]));
        #pragma unroll
        for (int off = 1; off < 16; off <<= 1)
            #pragma unroll
            for (int r = 0; r < 4; ++r) mx[r] = fmaxf(mx[r], __shfl_xor(mx[r], off));
        float al[4], rs[4] = {0.f, 0.f, 0.f, 0.f};
        #pragma unroll
        for (int r = 0; r < 4; ++r) {
            float mn = fmaxf(m_[r], mx[r]);
            al[r] = __expf(m_[r] - mn);
            m_[r] = mn;
        }
        float p[4][4];
        #pragma unroll
        for (int n = 0; n < 4; ++n)
            #pragma unroll
            for (int r = 0; r < 4; ++r) {
                p[n][r] = __expf(Sf[n][r] - m_[r]);
                rs[r] += p[n][r];
            }
        #pragma unroll
        for (int off = 1; off < 16; off <<= 1)
            #pragma unroll
            for (int r = 0; r < 4; ++r) rs[r] += __shfl_xor(rs[r], off);
        #pragma unroll
        for (int r = 0; r < 4; ++r) l_[r] = l_[r] * al[r] + rs[r];
        #pragma unroll
        for (int n = 0; n < 4; ++n)
            #pragma unroll
            for (int r = 0; r < 4; ++r) O[n][r] *= al[r];

        // ---- P -> LDS (C-layout rows -> A-layout rows; within-wave only) ----
        #pragma unroll
        for (int n = 0; n < 4; ++n)
            #pragma unroll
            for (int r = 0; r < 4; ++r)
                Ps[w * 16 + quad * 4 + r][n * 16 + li] = (__bf16)p[n][r];

        // ---- O += P V ----
        #pragma unroll
        for (int kc = 0; kc < 2; ++kc) {
            bf16x8 Ap = *(const bf16x8*)&Ps[w * 16 + li][kc * 32 + quad * 8];
            #pragma unroll
            for (int n = 0; n < 4; ++n) {
                bf16x8 Bv = *(const bf16x8*)&Vt[n * 16 + li][kc * 32 + quad * 8];
                O[n] = __builtin_amdgcn_mfma_f32_16x16x32_bf16(Ap, Bv, O[n], 0, 0, 0);
            }
        }
    }

    float inv[4];
    #pragma unroll
    for (int r = 0; r < 4; ++r) inv[r] = 1.0f / l_[r];
    #pragma unroll
    for (int n = 0; n < 4; ++n)
        #pragma unroll
        for (int r = 0; r < 4; ++r)
            ao[((size_t)b * Sn + q0 + w * 16 + quad * 4 + r) * Dn + hh * HDn + n * 16 + li]
                = (__bf16)(O[n][r] * inv[r]);
}

// ---------------- Kernel 7: MFMA GEMM  out = ao @ Wo^T + bo ------------------
// grid: 64 m-tiles x 8 n-tiles, 256 thr = 4 waves; wave w owns m-rows w*16..+16
// Both fragments are row-major contiguous-in-k (same shape as k_attn QK^T).
__global__ __launch_bounds__(256) void k_proj(
        const __bf16* __restrict__ ao, const float* __restrict__ Wo,
        const float* __restrict__ bo, float* __restrict__ out) {
    __shared__ __align__(16) __bf16 As[64][72];
    __shared__ __align__(16) __bf16 Bs[64][72];   // Bs[n][k] = Wo[n0+n][k0+k]
    int bm = blockIdx.x >> 3;
    int bn = blockIdx.x & 7;
    int m0 = bm * 64, n0 = bn * 64;
    int t = threadIdx.x;
    int w = t >> 6, lane = t & 63, quad = lane >> 4, li = lane & 15;

    f32x4 O[4];
    #pragma unroll
    for (int n = 0; n < 4; ++n) O[n] = (f32x4){0.f, 0.f, 0.f, 0.f};

    for (int k0 = 0; k0 < Dn; k0 += 64) {
        if (k0) __syncthreads();
        #pragma unroll
        for (int it = 0; it < 2; ++it) {          // A: 4096 bf16, 16B/thread/iter
            int e = (it * 256 + t) * 8; int r = e >> 6, c = e & 63;
            *(bf16x8*)&As[r][c] = *(const bf16x8*)&ao[(size_t)(m0 + r) * Dn + k0 + c];
        }
        #pragma unroll
        for (int it = 0; it < 4; ++it) {          // B: 4096 f32 -> bf16
            int e = (it * 256 + t) * 4; int r = e >> 6, c = e & 63;
            float4 wv = *(const float4*)&Wo[(size_t)(n0 + r) * Dn + k0 + c];
            bf16x4 bv = { (__bf16)wv.x, (__bf16)wv.y, (__bf16)wv.z, (__bf16)wv.w };
            *(bf16x4*)&Bs[r][c] = bv;
        }
        __syncthreads();

        bf16x8 A0 = *(const bf16x8*)&As[w * 16 + li][quad * 8];
        bf16x8 A1 = *(const bf16x8*)&As[w * 16 + li][32 + quad * 8];
        #pragma unroll
        for (int n = 0; n < 4; ++n) {
            bf16x8 B0 = *(const bf16x8*)&Bs[n * 16 + li][quad * 8];
            O[n] = __builtin_amdgcn_mfma_f32_16x16x32_bf16(A0, B0, O[n], 0, 0, 0);
            bf16x8 B1 = *(const bf16x8*)&Bs[n * 16 + li][32 + quad * 8];
            O[n] = __builtin_amdgcn_mfma_f32_16x16x32_bf16(A1, B1, O[n], 0, 0, 0);
        }
    }

    #pragma unroll
    for (int n = 0; n < 4; ++n) {
        float bias = bo[n0 + n * 16 + li];
        #pragma unroll
        for (int r = 0; r < 4; ++r)
            out[(size_t)(m0 + w * 16 + quad * 4 + r) * Dn + n0 + n * 16 + li] = O[n][r] + bias;
    }
}

extern "C" void kernel_launch(void* const* d_in, const int* in_sizes, int n_in,
                              void* d_out, int out_size, void* d_ws, size_t ws_size,
                              hipStream_t stream) {
    const int*   x   = (const int*)d_in[0];
    const float* emb = (const float*)d_in[1];
    const float* Wq  = (const float*)d_in[2];
    const float* Wk  = (const float*)d_in[3];
    const float* Wv  = (const float*)d_in[4];
    const float* Wo  = (const float*)d_in[5];
    const float* bo  = (const float*)d_in[6];
    const float* Wc  = (const float*)d_in[7];
    const float* bc  = (const float*)d_in[8];

    float* ws    = (float*)d_ws;
    float* h     = ws;                       // reused as ao (bf16) after k_qkv
    float* width = h + (size_t)Bn * Sn * Dn;
    float* lo    = width + Bn * Sn;
    float* hi    = lo + Bn;
    __bf16* qb   = (__bf16*)(hi + Bn);       // [B,H,S,HD]
    __bf16* kb   = qb + (size_t)Bn * Sn * Dn;
    __bf16* vtb  = kb + (size_t)Bn * Sn * Dn; // [B,H,HD,S]
    __bf16* ao   = (__bf16*)h;               // h dead after k_qkv; bf16 [B,S,D]

    float* out      = (float*)d_out;                      // [B,S,D]
    float* mask_out = out + (size_t)Bn * Sn * Dn;         // [B,S,S]

    k_embed<<<4096, 256, 0, stream>>>(x, emb, h);
    k_width<<<(Bn * Sn) / 4, 256, 0, stream>>>(h, Wc, bc, width);
    k_minmax<<<Bn, 256, 0, stream>>>(width, lo, hi);
    k_mask<<<Bn * Sn, 256, 0, stream>>>(width, lo, hi, mask_out);
    k_qkv<<<(Bn * Sn) / 8, 512, 0, stream>>>(h, Wq, Wk, Wv, qb, kb, vtb);
    k_attn<<<Bn * Hn * (Sn / 64), 256, 0, stream>>>(qb, kb, vtb, mask_out, ao);
    k_proj<<<(Bn * Sn / 64) * (Dn / 64), 256, 0, stream>>>(ao, Wo, bo, out);
}